// Round 1
// baseline (20.129 us; speedup 1.0000x reference)
//
#include <hip/hip_runtime.h>
#include <hip/hip_bf16.h>

// Hierarchical softmax loss:
//   loss = (1/B) * sum_b sum_{l=0..L-1} -log(sigmoid(scores[b, 2^l - 1 + bit_l]))
// where bit_l = (class_indices[b] >> (L-1-l)) & 1, L = ceil(log2(V)).
// Only 16 scattered floats per row are ever read -> latency-bound tiny kernel.

__global__ __launch_bounds__(1024) void hsm_loss_kernel(
    const float* __restrict__ scores,
    const int* __restrict__ class_indices,
    float* __restrict__ out,
    int B, int V, int code_len) {

    __shared__ float wave_part[16];  // up to 1024/64 waves

    float acc = 0.0f;
    // one thread per row (B == blockDim.x in the target shape; loop for safety)
    for (int b = threadIdx.x; b < B; b += blockDim.x) {
        const float* row = scores + (size_t)b * (size_t)V;
        const int ci = class_indices[b];
        #pragma unroll 16
        for (int l = 0; l < code_len; ++l) {
            const int shift = code_len - 1 - l;
            const int bit = (ci >> shift) & 1;
            const int col = (1 << l) - 1 + bit;   // scores column (padded idx - 1)
            const float x = row[col];
            // softplus(-x) = -log(sigmoid(x)), numerically stable form
            acc += log1pf(__expf(-fabsf(x))) + fmaxf(-x, 0.0f);
        }
    }

    // wave (64-lane) reduction
    #pragma unroll
    for (int off = 32; off > 0; off >>= 1)
        acc += __shfl_down(acc, off, 64);

    const int lane = threadIdx.x & 63;
    const int wid  = threadIdx.x >> 6;
    const int nwaves = (blockDim.x + 63) >> 6;
    if (lane == 0) wave_part[wid] = acc;
    __syncthreads();

    if (wid == 0) {
        float v = (lane < nwaves) ? wave_part[lane] : 0.0f;
        #pragma unroll
        for (int off = 32; off > 0; off >>= 1)
            v += __shfl_down(v, off, 64);
        if (lane == 0) out[0] = v / (float)B;
    }
}

extern "C" void kernel_launch(void* const* d_in, const int* in_sizes, int n_in,
                              void* d_out, int out_size, void* d_ws, size_t ws_size,
                              hipStream_t stream) {
    const float* scores = (const float*)d_in[0];
    const int* class_indices = (const int*)d_in[1];
    float* out = (float*)d_out;

    const int B = in_sizes[1];                 // class_indices: [B]
    const int V = (int)(in_sizes[0] / (size_t)in_sizes[1]);  // scores: [B, V]

    // code_len = ceil(log2(V))
    int code_len = 0;
    while ((1LL << code_len) < (long long)V) ++code_len;

    const int threads = 1024;
    hsm_loss_kernel<<<1, threads, 0, stream>>>(scores, class_indices, out, B, V, code_len);
}

// Round 2
// 11.404 us; speedup vs baseline: 1.7651x; 1.7651x over previous
//
#include <hip/hip_runtime.h>
#include <hip/hip_bf16.h>

// Hierarchical softmax loss:
//   loss = (1/B) * sum_b sum_{l=0..L-1} softplus(-scores[b, 2^l - 1 + bit_l])
// where bit_l = (class_indices[b] >> (L-1-l)) & 1, L = ceil(log2(V)).
// Only ~13 distinct cache lines per row are touched. Kernel A spreads the
// gather over 64 CUs (one thread per (row, level)); kernel B reduces partials.

__global__ __launch_bounds__(256) void hsm_partial_kernel(
    const float* __restrict__ scores,
    const int* __restrict__ class_indices,
    float* __restrict__ partials,
    int B, int V, int code_len) {

    const int tid = threadIdx.x;
    const int lvl0 = tid & 15;         // level lane within the row's 16 threads
    const int rowInBlk = tid >> 4;     // 16 rows per block
    const int r = blockIdx.x * 16 + rowInBlk;

    float acc = 0.0f;
    if (r < B) {
        const int ci = class_indices[r];             // 16-way same-address broadcast
        const float* row = scores + (size_t)r * (size_t)V;
        for (int l = lvl0; l < code_len; l += 16) {  // one iter when code_len==16
            const int shift = code_len - 1 - l;
            const int bit = (ci >> shift) & 1;
            const int col = (1 << l) - 1 + bit;
            const float x = row[col];
            // softplus(-x) = -log(sigmoid(x)), numerically stable
            acc += log1pf(__expf(-fabsf(x))) + fmaxf(-x, 0.0f);
        }
    }

    // block reduction: 4 waves of 64
    #pragma unroll
    for (int off = 32; off > 0; off >>= 1)
        acc += __shfl_down(acc, off, 64);

    __shared__ float wsum[4];
    const int lane = tid & 63;
    const int wid = tid >> 6;
    if (lane == 0) wsum[wid] = acc;
    __syncthreads();
    if (tid == 0)
        partials[blockIdx.x] = wsum[0] + wsum[1] + wsum[2] + wsum[3];
}

__global__ __launch_bounds__(64) void hsm_final_kernel(
    const float* __restrict__ partials, float* __restrict__ out,
    int nparts, int B) {
    float v = 0.0f;
    for (int i = threadIdx.x; i < nparts; i += 64) v += partials[i];
    #pragma unroll
    for (int off = 32; off > 0; off >>= 1)
        v += __shfl_down(v, off, 64);
    if (threadIdx.x == 0) out[0] = v / (float)B;
}

extern "C" void kernel_launch(void* const* d_in, const int* in_sizes, int n_in,
                              void* d_out, int out_size, void* d_ws, size_t ws_size,
                              hipStream_t stream) {
    const float* scores = (const float*)d_in[0];
    const int* class_indices = (const int*)d_in[1];
    float* out = (float*)d_out;
    float* partials = (float*)d_ws;

    const int B = in_sizes[1];                                // class_indices: [B]
    const int V = (int)(in_sizes[0] / (size_t)in_sizes[1]);   // scores: [B, V]

    int code_len = 0;
    while ((1LL << code_len) < (long long)V) ++code_len;

    const int rowsPerBlk = 16;
    const int grid = (B + rowsPerBlk - 1) / rowsPerBlk;       // 64 for B=1024

    hsm_partial_kernel<<<grid, 256, 0, stream>>>(scores, class_indices, partials,
                                                 B, V, code_len);
    hsm_final_kernel<<<1, 64, 0, stream>>>(partials, out, grid, B);
}